// Round 7
// baseline (285.550 us; speedup 1.0000x reference)
//
#include <hip/hip_runtime.h>
#include <hip/hip_bf16.h>
#include <cmath>

// Problem constants (Qwen3 MoE block)
constexpr int T = 2048;   // tokens (B*S)
constexpr int H = 1024;   // hidden
constexpr int I = 768;    // intermediate
constexpr int E = 16;     // experts
constexpr int WMAX = 48;  // max M-tiles at M=128: sum ceil(n_e/128) <= 47

// Transform decomposition: block = (matrix, e, 16-row group), 2 passes x 8 rows.
// gate: 16e * 48 groups = 768; up: 768; down: 16e * 64 = 1024.  Total 2560.
constexpr int CVT_ITEMS = 2560;
constexpr int RTR_BLOCKS = T / 8;        // 256
// LDS layout (shorts): ks-slice stride 328 (8 rows x 40 + pad, mult of 8),
// row stride 40. Chosen for 16B-aligned b128 phase-2 reads, ~2-way max.
constexpr int KSS = 328;
constexpr int RS  = 40;

typedef short short8  __attribute__((ext_vector_type(8)));
typedef short short4v __attribute__((ext_vector_type(4)));
typedef float f32x4   __attribute__((ext_vector_type(4)));

__device__ __forceinline__ short f2bf(float f) {
    __hip_bfloat16 h = __float2bfloat16(f);   // RNE
    return *reinterpret_cast<short*>(&h);
}

__device__ __forceinline__ short8 pack8(float4 a, float4 b) {
    short8 v = {f2bf(a.x), f2bf(a.y), f2bf(a.z), f2bf(a.w),
                f2bf(b.x), f2bf(b.y), f2bf(b.z), f2bf(b.w)};
    return v;
}

// XOR-swizzled LDS index for the GEMMs (units: shorts). Proven conflict-free.
__device__ __forceinline__ int sw(int r, int kg) {
    return r * 32 + (((kg + (r >> 1)) & 3) << 3);
}

// Uniform prefix scan over cnt[] (replaces a worklist kernel).
__device__ __forceinline__ bool find_item(const int* __restrict__ cnt, int bx,
                                          int& e_o, int& t0_o, int& n_o) {
    int c = 0;
    #pragma unroll
    for (int e = 0; e < E; ++e) {
        int n = cnt[e];
        int m = (n + 127) >> 7;
        if (bx < c + m) { e_o = e; t0_o = (bx - c) << 7; n_o = n; return true; }
        c += m;
    }
    return false;
}

// ------------------------------------------------------------------
// Transform core: 16 source rows (CONTIGUOUS region, 16*K floats)
// -> chunk-major bf16 tiles. 2 passes x 8 rows:
//  phase 1: fully LINEAR read (wave instr = 4 KB contiguous), cvt,
//           store to LDS chunk-major.
//  phase 2: per half-wave 512 B contiguous global write per chunk
//           run; write scatter across chunks is L2-combined.
// dst points at panel + r0base*32 (r0base = 16-row group offset).
// ------------------------------------------------------------------
template<int K, int R>   // R = 8*K/1024 rounds per pass
__device__ __forceinline__ void xform(const float* __restrict__ src,
                                      short* __restrict__ dst,
                                      short* __restrict__ lds, int tid) {
    #pragma unroll
    for (int pass = 0; pass < 2; ++pass) {
        const float* sp = src + (size_t)(pass * 8) * K;
        #pragma unroll
        for (int t = 0; t < R; ++t) {
            int o = (t * 256 + tid) * 4;           // linear float offset
            int lr = o / K;                        // const div (K literal)
            int k = o - lr * K;
            float4 v = *(const float4*)(sp + o);
            short4v s = {f2bf(v.x), f2bf(v.y), f2bf(v.z), f2bf(v.w)};
            *(short4v*)&lds[(k >> 5) * KSS + lr * RS + (k & 31)] = s;
        }
        __syncthreads();
        short* dq = dst + pass * 8 * 32;
        #pragma unroll
        for (int w = 0; w < R / 2; ++w) {
            int flat = w * 2048 + tid * 8;         // [0, 8*K)
            int ks = flat >> 8, p = flat & 255;    // chunk, pos-in-run
            *(short8*)(dq + (size_t)ks * 2048 + p) =
                *(const short8*)&lds[ks * KSS + (p >> 5) * RS + (p & 31)];
        }
        __syncthreads();
    }
}

// ------------------------------------------------------------------
// prep: fused {weight transform | router}.
// ------------------------------------------------------------------
__global__ __launch_bounds__(256) void prep_kernel(
    const float* __restrict__ x,     // [T,H]
    const float* __restrict__ gw,    // [E,H]
    const float* __restrict__ gp,    // [E,I,H] f32
    const float* __restrict__ up,    // [E,I,H] f32
    const float* __restrict__ dp,    // [E,H,I] f32
    short* __restrict__ xb,          // [T,H] bf16
    short* __restrict__ wtg,         // tiled bf16 gate
    short* __restrict__ wtu,         // tiled bf16 up
    short* __restrict__ wtd,         // tiled bf16 down
    int* __restrict__ cnt,           // [E]
    int* __restrict__ entries,       // [E,T]  value = t*2 + k
    float* __restrict__ wlist)       // [E,T]
{
    __shared__ short lds[32 * KSS];  // 21 KB transform staging
    __shared__ float lg[8][16][2];   // router logits

    const int tid = threadIdx.x;
    const int bid = blockIdx.x;

    if (bid < CVT_ITEMS) {
        if (bid < 1536) {            // gate / up: rows = I, K = H
            const bool isu = bid >= 768;
            const int id3 = isu ? bid - 768 : bid;
            const int e = id3 / 48, rem = id3 - e * 48;
            const int rb = rem >> 2, q4 = rem & 3;   // 64-row block, quarter
            const float* src = (isu ? up : gp)
                + (size_t)e * (I * H) + (size_t)(rb * 64 + q4 * 16) * H;
            short* dst = (isu ? wtu : wtg)
                + ((size_t)(e * 12 + rb) * 32) * 2048 + q4 * 16 * 32;
            xform<1024, 8>(src, dst, lds, tid);
        } else {                     // down: rows = H, K = I
            const int id3 = bid - 1536;
            const int e = id3 / 64, rem = id3 - e * 64;
            const int rb = rem >> 2, q4 = rem & 3;
            const float* src = dp
                + (size_t)e * (H * I) + (size_t)(rb * 64 + q4 * 16) * I;
            short* dst = wtd
                + ((size_t)(e * 16 + rb) * 24) * 2048 + q4 * 16 * 32;
            xform<768, 6>(src, dst, lds, tid);
        }
        return;
    }

    // ---- router block ----
    const int rb = bid - CVT_ITEMS;
    const int tl = tid & 7;              // token
    const int e  = (tid >> 3) & 15;      // expert
    const int hf = tid >> 7;             // H-half
    const int t  = rb * 8 + tl;

    const float4* xr = (const float4*)(x + (size_t)t * H);
    const float4* gr = (const float4*)(gw + (size_t)e * H);
    short* xrow = xb + (size_t)t * H;

    float s0 = 0.f, s1 = 0.f;
    const int qlo = hf * 128, qhi = qlo + 128;
    #pragma unroll 8
    for (int q = qlo; q < qhi; q += 2) {
        float4 a = xr[q],     b = gr[q];
        float4 c = xr[q + 1], d = gr[q + 1];
        s0 += a.x * b.x + a.y * b.y + a.z * b.z + a.w * b.w;
        s1 += c.x * d.x + c.y * d.y + c.z * d.z + c.w * d.w;
        if (((q >> 3) & 15) == e)
            *(short8*)(xrow + q * 4) = pack8(a, c);   // 16B-aligned (q even)
    }

    lg[tl][e][hf] = s0 + s1;
    __syncthreads();

    if (tid < 8) {
        int tk = rb * 8 + tid;
        float v1 = -3.0e38f, v2 = -3.0e38f;
        int i1 = 0, i2 = 0;
        #pragma unroll
        for (int k = 0; k < E; ++k) {
            float v = lg[tid][k][0] + lg[tid][k][1];
            if (v > v1) { v2 = v1; i2 = i1; v1 = v; i1 = k; }
            else if (v > v2) { v2 = v; i2 = k; }
        }
        // renormalized top-2 softmax == softmax over the two winning logits
        float w1 = 1.f / (1.f + expf(v2 - v1));
        float w2 = 1.f - w1;
        int p = atomicAdd(&cnt[i1], 1);
        entries[i1 * T + p] = tk * 2;
        wlist[i1 * T + p] = w1;
        p = atomicAdd(&cnt[i2], 1);
        entries[i2 * T + p] = tk * 2 + 1;
        wlist[i2 * T + p] = w2;
    }
}

// ------------------------------------------------------------------
// Grouped gate/up GEMM + SwiGLU, bf16 MFMA. Tile M=128 x NI=64,
// BK=32. Weights from the bf16 tile buffer: 1 short8/thread/K-step,
// contiguous 128 KB stream per block. (Unchanged from round 6.)
// ------------------------------------------------------------------
__global__ __launch_bounds__(256) void gateup_mfma(
    const short* __restrict__ xb,      // [T,H] bf16
    const short* __restrict__ wtg,     // tiled bf16 gate
    const short* __restrict__ wtu,     // tiled bf16 up
    const int* __restrict__ cnt,
    const int* __restrict__ entries,
    short* __restrict__ hmid)          // [2T,I] bf16, row = slot = t*2+k
{
    int e, t0, n;
    if (!find_item(cnt, blockIdx.x, e, t0, n)) return;
    const int i0 = blockIdx.y * 64;

    __shared__ short Xs[128 * 32];
    __shared__ short Gs[64 * 32];
    __shared__ short Us[64 * 32];
    __shared__ int toks[128];

    const int tid = threadIdx.x;
    if (tid < 128) {
        int r = t0 + tid;
        toks[tid] = (r < n) ? entries[e * T + r] : -1;
    }
    __syncthreads();

    const int lane = tid & 63, wave = tid >> 6;
    const int m16 = lane & 15, q = lane >> 4;

    const int sr = tid >> 2, skg = tid & 3;
    const int xt0 = toks[sr], xt1 = toks[64 + sr];
    const short* xsrc0 = xb + (size_t)((xt0 >= 0 ? xt0 : 0) >> 1) * H + skg * 8;
    const short* xsrc1 = xb + (size_t)((xt1 >= 0 ? xt1 : 0) >> 1) * H + skg * 8;
    const short* gts = wtg + ((size_t)(e * 12 + blockIdx.y) * 32) * 2048 + tid * 8;
    const short* uts = wtu + ((size_t)(e * 12 + blockIdx.y) * 32) * 2048 + tid * 8;

    f32x4 accg[8], accu[8];
    #pragma unroll
    for (int a = 0; a < 8; ++a) {
        accg[a] = (f32x4){0.f, 0.f, 0.f, 0.f};
        accu[a] = (f32x4){0.f, 0.f, 0.f, 0.f};
    }

    short8 xc0 = *(const short8*)xsrc0;
    short8 xc1 = *(const short8*)xsrc1;
    short8 gt = *(const short8*)gts;
    short8 ut = *(const short8*)uts;

    for (int ks = 0; ks < H / 32; ++ks) {
        *(short8*)&Xs[sw(sr, skg)]      = xc0;
        *(short8*)&Xs[sw(64 + sr, skg)] = xc1;
        *(short8*)&Gs[sw(sr, skg)] = gt;
        *(short8*)&Us[sw(sr, skg)] = ut;
        int ksn = (ks + 1 < H / 32) ? ks + 1 : 0;
        int kn = ksn * 32;
        xc0 = *(const short8*)(xsrc0 + kn);
        xc1 = *(const short8*)(xsrc1 + kn);
        gt = *(const short8*)(gts + ksn * 2048);
        ut = *(const short8*)(uts + ksn * 2048);
        __syncthreads();

        short8 bg = *(const short8*)&Gs[sw(wave * 16 + m16, q)];
        short8 bu = *(const short8*)&Us[sw(wave * 16 + m16, q)];
        #pragma unroll
        for (int mi = 0; mi < 8; ++mi) {
            short8 af = *(const short8*)&Xs[sw(mi * 16 + m16, q)];
            accg[mi] = __builtin_amdgcn_mfma_f32_16x16x32_bf16(af, bg, accg[mi], 0, 0, 0);
            accu[mi] = __builtin_amdgcn_mfma_f32_16x16x32_bf16(af, bu, accu[mi], 0, 0, 0);
        }
        __syncthreads();
    }

    const int col = i0 + wave * 16 + m16;
    #pragma unroll
    for (int mi = 0; mi < 8; ++mi)
        #pragma unroll
        for (int j = 0; j < 4; ++j) {
            int row = mi * 16 + q * 4 + j;
            int slot = toks[row];
            if (slot < 0) continue;
            float g = accg[mi][j];
            float u = accu[mi][j];
            float hv = g / (1.f + expf(-g)) * u;
            ((unsigned short*)hmid)[(size_t)slot * I + col] = (unsigned short)f2bf(hv);
        }
}

// ------------------------------------------------------------------
// Grouped down GEMM. Tile M=128 x N=64, BK=32 (24 K-steps).
// f32 atomic combine. (Unchanged from round 6.)
// ------------------------------------------------------------------
__global__ __launch_bounds__(256) void down_mfma(
    const short* __restrict__ hmid,    // [2T,I] bf16
    const short* __restrict__ wtd,     // tiled bf16 down
    const int* __restrict__ cnt,
    const int* __restrict__ entries,
    const float* __restrict__ wlist,
    float* __restrict__ out)           // [T,H], pre-zeroed
{
    int e, t0, n;
    if (!find_item(cnt, blockIdx.x, e, t0, n)) return;
    const int h0 = blockIdx.y * 64;

    __shared__ short As[128 * 32];
    __shared__ short Bs[64 * 32];
    __shared__ int toks[128];
    __shared__ float wr[128];

    const int tid = threadIdx.x;
    if (tid < 128) {
        int r = t0 + tid;
        bool v = (r < n);
        toks[tid] = v ? entries[e * T + r] : -1;
        wr[tid]   = v ? wlist[e * T + r] : 0.f;
    }
    __syncthreads();

    const int lane = tid & 63, wave = tid >> 6;
    const int m16 = lane & 15, q = lane >> 4;

    const int sr = tid >> 2, skg = tid & 3;
    const int at0 = toks[sr], at1 = toks[64 + sr];
    const short* asrc0 = hmid + (size_t)(at0 >= 0 ? at0 : 0) * I + skg * 8;
    const short* asrc1 = hmid + (size_t)(at1 >= 0 ? at1 : 0) * I + skg * 8;
    const short* bts = wtd + ((size_t)(e * 16 + blockIdx.y) * 24) * 2048 + tid * 8;

    f32x4 acc[8];
    #pragma unroll
    for (int a = 0; a < 8; ++a) acc[a] = (f32x4){0.f, 0.f, 0.f, 0.f};

    short8 ac0 = *(const short8*)asrc0;
    short8 ac1 = *(const short8*)asrc1;
    short8 bt = *(const short8*)bts;

    for (int ks = 0; ks < I / 32; ++ks) {
        *(short8*)&As[sw(sr, skg)]      = ac0;
        *(short8*)&As[sw(64 + sr, skg)] = ac1;
        *(short8*)&Bs[sw(sr, skg)]      = bt;
        int ksn = (ks + 1 < I / 32) ? ks + 1 : 0;
        int kn = ksn * 32;
        ac0 = *(const short8*)(asrc0 + kn);
        ac1 = *(const short8*)(asrc1 + kn);
        bt = *(const short8*)(bts + ksn * 2048);
        __syncthreads();

        short8 bf = *(const short8*)&Bs[sw(wave * 16 + m16, q)];
        #pragma unroll
        for (int mi = 0; mi < 8; ++mi) {
            short8 af = *(const short8*)&As[sw(mi * 16 + m16, q)];
            acc[mi] = __builtin_amdgcn_mfma_f32_16x16x32_bf16(af, bf, acc[mi], 0, 0, 0);
        }
        __syncthreads();
    }

    const int col = h0 + wave * 16 + m16;
    #pragma unroll
    for (int mi = 0; mi < 8; ++mi)
        #pragma unroll
        for (int j = 0; j < 4; ++j) {
            int row = mi * 16 + q * 4 + j;
            int slot = toks[row];
            if (slot < 0) continue;
            atomicAdd(&out[(size_t)(slot >> 1) * H + col], wr[row] * acc[mi][j]);
        }
}

extern "C" void kernel_launch(void* const* d_in, const int* in_sizes, int n_in,
                              void* d_out, int out_size, void* d_ws, size_t ws_size,
                              hipStream_t stream) {
    const float* x  = (const float*)d_in[0];   // [1,2048,1024]
    const float* gw = (const float*)d_in[1];   // [16,1024]
    const float* gp = (const float*)d_in[2];   // [16,768,1024]
    const float* up = (const float*)d_in[3];   // [16,768,1024]
    const float* dp = (const float*)d_in[4];   // [16,1024,768]
    float* out = (float*)d_out;

    char* ws = (char*)d_ws;
    int*   cnt     = (int*)ws;                       // 16 ints
    int*   entries = (int*)(ws + 2048);              // E*T ints   (128 KB)
    float* wlist   = (float*)(ws + 2048 + 131072);   // E*T floats (128 KB)
    short* xb      = (short*)(ws + 2048 + 262144);   // T*H bf16   (4 MB)
    short* hmid    = xb + (size_t)T * H;             // 2T*I bf16  (6 MB)
    short* wtg     = hmid + (size_t)2 * T * I;       // 24 MB bf16 tiled gate
    short* wtu     = wtg + (size_t)E * I * H;        // 24 MB bf16 tiled up
    short* wtd     = wtu + (size_t)E * I * H;        // 24 MB bf16 tiled down
    // ws_size >= ~86.3 MB proven on this harness (rounds 5-6 ran tiled).

    hipMemsetAsync(ws, 0, 2048, stream);
    hipMemsetAsync(out, 0, (size_t)T * H * sizeof(float), stream);

    prep_kernel<<<CVT_ITEMS + RTR_BLOCKS, 256, 0, stream>>>(
        x, gw, gp, up, dp, xb, wtg, wtu, wtd, cnt, entries, wlist);
    gateup_mfma<<<dim3(WMAX, I / 64), 256, 0, stream>>>(
        xb, wtg, wtu, cnt, entries, hmid);
    down_mfma<<<dim3(WMAX, H / 64), 256, 0, stream>>>(
        hmid, wtd, cnt, entries, wlist, out);
}